// Round 4
// baseline (540.499 us; speedup 1.0000x reference)
//
#include <hip/hip_runtime.h>

// VQ-VAE forward on MI355X, fp32 (no fp32 MFMA on CDNA4 -> vector ALU).
// N = 65536 rows, IN_DIM=256, D=64, K=512.
//
// Key structure: in every GEMM one operand is wave-uniform (enc_w / codebook).
// Uniform operand streams through SGPRs (s_load, scalar pipe, free VALU src);
// each lane owns one row in VGPRs. Inner loops are pure v_fma — zero LDS.
//
// ws layout (bytes):
//   z:      float[65536*64]  @ 0          (16 MiB)
//   idx:    int[65536]       @ 16777216   (256 KiB)
//   cr:     float[512*256]   @ 17039360   (512 KiB)  = codebook @ dec_w
//   sse:    double           @ 17563648
//   counts: int[512]         @ 17563656   (2 KiB)
//   ees:    float[512]       @ 17565704   (2 KiB)    = ||e_k||^2 (ref fma order)

__device__ __forceinline__ unsigned ford(float s) {
    // order-preserving map float -> unsigned (total order, matches < on floats)
    unsigned b = __float_as_uint(s);
    return (b & 0x80000000u) ? ~b : (b | 0x80000000u);
}

// ---------------- K1: z = x @ enc_w  ([65536,256]x[256,64]) ----------------
// 1024 blocks x 128 threads (2 waves). Lane owns row = blockIdx*64+lane;
// wave `half` computes output dims [half*32, half*32+32). enc_w rows arrive
// via uniform s_load; x row chunk (64 floats) lives in VGPRs.
// acc[d] accumulates k=0..255 strictly in order -> bit-identical z to r1-r3.
__global__ __launch_bounds__(128) void k_encode(const float* __restrict__ x,
                                                const float* __restrict__ enc_w,
                                                float* __restrict__ z) {
    int t = threadIdx.x;
    int lane = t & 63, half = t >> 6;
    int row = blockIdx.x * 64 + lane;

    const float4* xr4 = (const float4*)(x + (size_t)row * 256);  // per-lane row
    const float4* w4 = (const float4*)enc_w;                     // [k][16 f4]

    float acc[32];
#pragma unroll
    for (int d = 0; d < 32; ++d) acc[d] = 0.f;

    for (int c = 0; c < 4; ++c) {       // k chunks of 64
        float4 xc[16];
#pragma unroll
        for (int j = 0; j < 16; ++j) xc[j] = xr4[c * 16 + j];

#pragma unroll
        for (int j16 = 0; j16 < 16; ++j16) {
            float4 xv = xc[j16];
            int kb = c * 64 + j16 * 4;
#pragma unroll
            for (int s = 0; s < 4; ++s) {
                float xk = (s == 0) ? xv.x : (s == 1) ? xv.y : (s == 2) ? xv.z : xv.w;
                int k = kb + s;
#pragma unroll
                for (int j = 0; j < 8; ++j) {
                    float4 wv = w4[k * 16 + half * 8 + j];  // uniform -> s_load
                    acc[4 * j + 0] = fmaf(xk, wv.x, acc[4 * j + 0]);
                    acc[4 * j + 1] = fmaf(xk, wv.y, acc[4 * j + 1]);
                    acc[4 * j + 2] = fmaf(xk, wv.z, acc[4 * j + 2]);
                    acc[4 * j + 3] = fmaf(xk, wv.w, acc[4 * j + 3]);
                }
            }
        }
    }
    float4* zr4 = (float4*)(z + (size_t)row * 64 + half * 32);
#pragma unroll
    for (int j = 0; j < 8; ++j)
        zr4[j] = make_float4(acc[4 * j], acc[4 * j + 1], acc[4 * j + 2], acc[4 * j + 3]);
}

// ---------------- K2: nearest-code assignment + loss/hist ----------------
// 512 blocks x 128 threads; thread owns one row (z row in 64 VGPRs).
// Codebook rows + ||e||^2 stream via uniform s_load. Zero-LDS inner loop.
// zz / ee / dot partials / s / ford / strict-< identical to passing rounds.
__global__ __launch_bounds__(128) void k_assign(const float* __restrict__ z,
                                                const float* __restrict__ cb,
                                                const float* __restrict__ ees_g,
                                                int* __restrict__ idx,
                                                double* __restrict__ sse,
                                                int* __restrict__ counts) {
    __shared__ int hist[512];
    int t = threadIdx.x;
    int row = blockIdx.x * 128 + t;

    for (int i = t; i < 512; i += 128) hist[i] = 0;

    const float4* zr4 = (const float4*)(z + (size_t)row * 64);
    float4 zc[16];
#pragma unroll
    for (int j = 0; j < 16; ++j) zc[j] = zr4[j];

    // ||z||^2, reference fma order
    float a0 = 0, a1 = 0, a2 = 0, a3 = 0;
#pragma unroll
    for (int j = 0; j < 16; ++j) {
        a0 = fmaf(zc[j].x, zc[j].x, a0);
        a1 = fmaf(zc[j].y, zc[j].y, a1);
        a2 = fmaf(zc[j].z, zc[j].z, a2);
        a3 = fmaf(zc[j].w, zc[j].w, a3);
    }
    float zz = (a0 + a1) + (a2 + a3);
    __syncthreads();  // hist init complete before any atomicAdd below

    const float4* cb4 = (const float4*)cb;
    unsigned bestU = 0xFFFFFFFFu;
    int bestC = 0;

    for (int k = 0; k < 512; ++k) {
        float ee = ees_g[k];  // uniform -> s_load
        float d0 = 0, d1 = 0, d2 = 0, d3 = 0;
#pragma unroll
        for (int j = 0; j < 16; ++j) {
            float4 ev = cb4[k * 16 + j];  // uniform -> s_load_dwordx4
            d0 = fmaf(zc[j].x, ev.x, d0);
            d1 = fmaf(zc[j].y, ev.y, d1);
            d2 = fmaf(zc[j].z, ev.z, d2);
            d3 = fmaf(zc[j].w, ev.w, d3);
        }
        float dot = (d0 + d1) + (d2 + d3);
        float s = fmaf(-2.0f, dot, zz + ee);  // == (zz+ee)-2f*dot
        unsigned u = ford(s);
        if (u < bestU) { bestU = u; bestC = k; }  // strict < keeps lowest code
    }

    idx[row] = bestC;
    atomicAdd(&hist[bestC], 1);

    // sse contribution (fp64, same per-element order as r1-r3)
    double accd = 0.0;
    const float4* q4 = (const float4*)(cb + (size_t)bestC * 64);
#pragma unroll
    for (int j = 0; j < 16; ++j) {
        float4 qv = q4[j];
        float4 zv = zc[j];
        float fx = qv.x - zv.x, fy = qv.y - zv.y;
        float fz = qv.z - zv.z, fw = qv.w - zv.w;
        accd += (double)fx * fx + (double)fy * fy + (double)fz * fz + (double)fw * fw;
    }
#pragma unroll
    for (int off = 32; off >= 1; off >>= 1) accd += __shfl_down(accd, off);
    if ((t & 63) == 0) atomicAdd(sse, accd);

    __syncthreads();  // all hist adds done
    for (int i = t; i < 512; i += 128)
        if (hist[i]) atomicAdd(&counts[i], hist[i]);
}

// ---------------- K3a: cr = codebook @ dec_w ; ees = ||e||^2 ----------------
// 512 blocks (one code each) x 256 threads (one output col each).
// cb row via uniform s_load; dec_w coalesced (64 KB, L2-hot).
// acc chain k=0..63 sequential -> bit-identical cr to r1-r3.
__global__ __launch_bounds__(256) void k_coderecon(const float* __restrict__ cb,
                                                   const float* __restrict__ dec_w,
                                                   float* __restrict__ cr,
                                                   float* __restrict__ ees_g) {
    int code = blockIdx.x;
    int col = threadIdx.x;
    const float4* cb4 = (const float4*)(cb + (size_t)code * 64);

    float acc = 0.f;
    float n0 = 0, n1 = 0, n2 = 0, n3 = 0;
#pragma unroll
    for (int j = 0; j < 16; ++j) {
        float4 ev = cb4[j];  // uniform -> s_load
        n0 = fmaf(ev.x, ev.x, n0);
        n1 = fmaf(ev.y, ev.y, n1);
        n2 = fmaf(ev.z, ev.z, n2);
        n3 = fmaf(ev.w, ev.w, n3);
        acc = fmaf(ev.x, dec_w[(4 * j + 0) * 256 + col], acc);
        acc = fmaf(ev.y, dec_w[(4 * j + 1) * 256 + col], acc);
        acc = fmaf(ev.z, dec_w[(4 * j + 2) * 256 + col], acc);
        acc = fmaf(ev.w, dec_w[(4 * j + 3) * 256 + col], acc);
    }
    cr[(size_t)code * 256 + col] = acc;
    if (col == 0) ees_g[code] = (n0 + n1) + (n2 + n3);
}

// ---------------- K3b: x_recon[row] = cr[idx[row]] (pure gather) ----------------
// out points at d_out+1 (4B-aligned only) -> dword stores.
__global__ __launch_bounds__(256) void k_gather(const float* __restrict__ cr,
                                                const int* __restrict__ idx,
                                                float* __restrict__ out) {
    int t = threadIdx.x;
    int row = blockIdx.x * 16 + (t >> 4);
    int k = idx[row];
    const float4* cr4 = (const float4*)(cr + (size_t)k * 256);
    float* o = out + (size_t)row * 256;
#pragma unroll
    for (int j = 0; j < 4; ++j) {
        int f4 = (t & 15) + 16 * j;
        float4 v = cr4[f4];
        o[f4 * 4 + 0] = v.x;
        o[f4 * 4 + 1] = v.y;
        o[f4 * 4 + 2] = v.z;
        o[f4 * 4 + 3] = v.w;
    }
}

// ---------------- K4: loss + perplexity scalars ----------------
__global__ __launch_bounds__(512) void k_final(const double* __restrict__ sse,
                                               const int* __restrict__ counts,
                                               float* __restrict__ out_loss,
                                               float* __restrict__ out_pp) {
    __shared__ double red[8];
    int t = threadIdx.x;
    double p = (double)counts[t] / 65536.0;
    double term = p * log(p + 1e-10);
#pragma unroll
    for (int off = 32; off >= 1; off >>= 1) term += __shfl_down(term, off);
    if ((t & 63) == 0) red[t >> 6] = term;
    __syncthreads();
    if (t == 0) {
        double s = 0;
#pragma unroll
        for (int w = 0; w < 8; ++w) s += red[w];
        out_pp[0] = (float)exp(-s);
        out_loss[0] = (float)(1.25 * sse[0] / 4194304.0);  // (1+0.25)*mean((q-z)^2)
    }
}

extern "C" void kernel_launch(void* const* d_in, const int* in_sizes, int n_in,
                              void* d_out, int out_size, void* d_ws, size_t ws_size,
                              hipStream_t stream) {
    const float* x = (const float*)d_in[0];
    const float* enc_w = (const float*)d_in[1];
    const float* dec_w = (const float*)d_in[2];
    const float* cb = (const float*)d_in[3];
    float* out = (float*)d_out;

    char* ws = (char*)d_ws;
    float* z = (float*)ws;                        // 16 MiB
    int* idx = (int*)(ws + 16777216);             // 256 KiB
    float* cr = (float*)(ws + 17039360);          // 512 KiB
    double* sse = (double*)(ws + 17563648);       // 8 B
    int* counts = (int*)(ws + 17563656);          // 2 KiB
    float* ees = (float*)(ws + 17565704);         // 2 KiB

    // ws is poisoned to 0xAA before each launch -> zero the accumulators
    hipMemsetAsync(ws + 17563648, 0, 8 + 2048, stream);

    k_coderecon<<<dim3(512), dim3(256), 0, stream>>>(cb, dec_w, cr, ees);
    k_encode<<<dim3(1024), dim3(128), 0, stream>>>(x, enc_w, z);
    k_assign<<<dim3(512), dim3(128), 0, stream>>>(z, cb, ees, idx, sse, counts);
    k_gather<<<dim3(4096), dim3(256), 0, stream>>>(cr, idx, out + 1);
    k_final<<<dim3(1), dim3(512), 0, stream>>>(sse, counts, out, out + 16777217);
}